// Round 7
// baseline (125.826 us; speedup 1.0000x reference)
//
#include <hip/hip_runtime.h>
#include <hip/hip_bf16.h>
#include <cstdint>
#include <cstddef>

// Problem constants (fixed by the reference setup)
#define BB 4
#define TT 2048
#define DM 1024
#define DH 64

typedef __attribute__((ext_vector_type(8))) short short8;   // 8 bf16 (4 VGPRs)
typedef __attribute__((ext_vector_type(4))) float floatx4;  // MFMA C/D

__device__ __forceinline__ unsigned short f2bf(float f) {
    union { float f; unsigned int u; } v; v.f = f;
    unsigned int u = v.u;
    u += 0x7fffu + ((u >> 16) & 1u);   // RNE; inputs are finite
    return (unsigned short)(u >> 16);
}

__device__ __forceinline__ float bf2f(unsigned short h) {
    union { unsigned int u; float f; } v;
    v.u = ((unsigned int)h) << 16;
    return v.f;
}

// HW packed f32->bf16 (RNE), 1 VALU op for 2 values. Non-volatile: scheduler-free.
__device__ __forceinline__ unsigned int cvtpk(float a, float b) {
    unsigned int r;
    asm("v_cvt_pk_bf16_f32 %0, %1, %2" : "=v"(r) : "v"(a), "v"(b));
    return r;
}

__device__ __forceinline__ short8 cvt8(float4 lo, float4 hi) {
    union { unsigned int u[4]; short8 s; } v;
    v.u[0] = cvtpk(lo.x, lo.y);
    v.u[1] = cvtpk(lo.z, lo.w);
    v.u[2] = cvtpk(hi.x, hi.y);
    v.u[3] = cvtpk(hi.z, hi.w);
    return v.s;
}

// ---------------------------------------------------------------------------
// Kernel 0: pre-tile W_Q/W_K into B-frag order (tiny: 512 KB out).
//   wbt[nt][kc][lane][8] = W[(nt&3)*16 + (lane&15)][kc*32 + (lane>>4)*8 + j]
//   nt 0-3 = W_Q, nt 4-7 = W_K.
// ---------------------------------------------------------------------------
#define WTHREADS (8 * 32 * 64)       // 16384: 64 blocks

__global__ __launch_bounds__(256) void wtile_kernel(const float* __restrict__ wq,
                                                    const float* __restrict__ wk,
                                                    unsigned short* __restrict__ wbt) {
    const int j  = blockIdx.x * 256 + threadIdx.x;   // 0..16383
    const int l  = j & 63;
    const int kc = (j >> 6) & 31;
    const int nt = j >> 11;                          // 0..7
    const float* wbase = (nt < 4) ? wq : wk;
    const float* src = wbase + (size_t)((nt & 3) * 16 + (l & 15)) * DM
                             + kc * 32 + (l >> 4) * 8;
    float4 a = *reinterpret_cast<const float4*>(src);
    float4 b = *reinterpret_cast<const float4*>(src + 4);
    *reinterpret_cast<short8*>(wbt + (size_t)j * 8) = cvt8(a, b);
}

// ---------------------------------------------------------------------------
// Kernel 1: fused convert + projection GEMM (2-half pipeline). 512 blocks x
// 4 waves; block owns one 16-row m-tile. Wave w: Q n-tile w, K n-tile 4+w.
// Q is pre-scaled by (1/sqrt(1024)) * log2(e) so flash can use exp2 directly.
// ---------------------------------------------------------------------------
__global__ __launch_bounds__(256) void proj_kernel(const float* __restrict__ x,
                                                   const unsigned short* __restrict__ wbt,
                                                   unsigned short* __restrict__ qo,
                                                   unsigned short* __restrict__ ko,
                                                   unsigned short* __restrict__ kt) {
    __shared__ __align__(16) unsigned short sA[2][16 * 64 * 8];  // 2 x 16 KB halves

    const int tid  = threadIdx.x;
    const int wave = tid >> 6;
    const int lane = tid & 63;
    const int col  = lane & 15;
    const int quad = lane >> 4;
    const int mt   = blockIdx.x;

    const float* xtile = x + (size_t)mt * 16 * DM;
    const unsigned short* bq = wbt + ((size_t)wave * 32 * 64) * 8;
    const unsigned short* bk = wbt + ((size_t)(4 + wave) * 32 * 64) * 8;

    floatx4 accQ = (floatx4){0.f, 0.f, 0.f, 0.f};
    floatx4 accK = (floatx4){0.f, 0.f, 0.f, 0.f};

    // ---- stage half 0 (kc 0..15) ----
#pragma unroll 4
    for (int i = 0; i < 4; ++i) {
        const int e  = tid + i * 256;          // 0..1023
        const int kc = e >> 6;
        const int l  = e & 63;
        const float* src = xtile + (size_t)(l & 15) * DM + kc * 32 + (l >> 4) * 8;
        float4 a = *reinterpret_cast<const float4*>(src);
        float4 b = *reinterpret_cast<const float4*>(src + 4);
        *reinterpret_cast<short8*>(sA[0] + (size_t)e * 8) = cvt8(a, b);
    }
    __syncthreads();

    // ---- issue half-1 loads (kc 16..31) BEFORE computing half 0 ----
    float4 h1a[4], h1b[4];
#pragma unroll 4
    for (int i = 0; i < 4; ++i) {
        const int e  = tid + i * 256;
        const int kc = 16 + (e >> 6);
        const int l  = e & 63;
        const float* src = xtile + (size_t)(l & 15) * DM + kc * 32 + (l >> 4) * 8;
        h1a[i] = *reinterpret_cast<const float4*>(src);
        h1b[i] = *reinterpret_cast<const float4*>(src + 4);
    }

    // ---- compute half 0 while half-1 loads are in flight ----
#pragma unroll
    for (int kc = 0; kc < 16; ++kc) {
        short8 a  = *reinterpret_cast<const short8*>(sA[0] + ((size_t)kc * 64 + lane) * 8);
        short8 b0 = *reinterpret_cast<const short8*>(bq + ((size_t)kc * 64 + lane) * 8);
        short8 b1 = *reinterpret_cast<const short8*>(bk + ((size_t)kc * 64 + lane) * 8);
        accQ = __builtin_amdgcn_mfma_f32_16x16x32_bf16(a, b0, accQ, 0, 0, 0);
        accK = __builtin_amdgcn_mfma_f32_16x16x32_bf16(a, b1, accK, 0, 0, 0);
    }

    // ---- write half 1 (separate buffer: no barrier needed before writes) ----
#pragma unroll 4
    for (int i = 0; i < 4; ++i) {
        const int e = tid + i * 256;
        *reinterpret_cast<short8*>(sA[1] + (size_t)e * 8) = cvt8(h1a[i], h1b[i]);
    }
    __syncthreads();

    // ---- compute half 1 ----
#pragma unroll
    for (int kc = 0; kc < 16; ++kc) {
        short8 a  = *reinterpret_cast<const short8*>(sA[1] + ((size_t)kc * 64 + lane) * 8);
        short8 b0 = *reinterpret_cast<const short8*>(bq + ((size_t)(16 + kc) * 64 + lane) * 8);
        short8 b1 = *reinterpret_cast<const short8*>(bk + ((size_t)(16 + kc) * 64 + lane) * 8);
        accQ = __builtin_amdgcn_mfma_f32_16x16x32_bf16(a, b0, accQ, 0, 0, 0);
        accK = __builtin_amdgcn_mfma_f32_16x16x32_bf16(a, b1, accK, 0, 0, 0);
    }

    // ---- epilogue: C/D layout col = lane&15, row = quad*4 + r ----
    // Q scale folds in log2(e): 1/32 * 1.44269504 = 0.04508422
    const int g = wave * 16 + col;             // output col 0..63
    unsigned short hk[4];
#pragma unroll
    for (int r = 0; r < 4; ++r) {
        const size_t row = (size_t)(mt * 16 + quad * 4 + r);
        qo[row * DH + g] = f2bf(accQ[r] * 0.04508422f);
        hk[r] = f2bf(accK[r]);
        ko[row * DH + g] = hk[r];
    }

    // ---- kt: transpose K tile through LDS (reuse sA), write 32B runs ----
    __syncthreads();                           // all waves done reading sA
    unsigned short* kts = (unsigned short*)sA; // [64 d][16 s] shorts, 2 KB
#pragma unroll
    for (int r = 0; r < 4; ++r)
        kts[g * 16 + quad * 4 + r] = hk[r];
    __syncthreads();
    if (tid < 128) {
        const int d  = tid >> 1;
        const int s8 = (tid & 1) * 8;
        const int b4 = mt >> 7;                       // batch
        const int s0 = (mt & 127) * 16 + s8;          // seq pos within batch
        short8 v = *reinterpret_cast<const short8*>(kts + d * 16 + s8);
        *reinterpret_cast<short8*>(kt + ((size_t)(b4 * 64 + d)) * TT + s0) = v;
    }
}

// ---------------------------------------------------------------------------
// Kernel 2: FUSED flash + merge, PAIR-BALANCED, IN-REGISTER SOFTMAX,
// 16 WAVES/BLOCK. Block = (b, pair p, half h) as before, but 1024 threads:
// grid 256 = 1 block/CU -> 4 waves/SIMD (was 2) to hide the ~200cy L2-hit
// latency of the per-body K/V loads. Waves split the 65-body list
// [(65w)>>4, (65(w+1))>>4) -> 4-5 bodies each. Swapped QK^T keeps P
// lane-local (no LDS round-trip). LDS-atomic merge as before.
// __launch_bounds__(1024, 4) caps VGPR at 128 to guarantee the occupancy.
// ---------------------------------------------------------------------------
__global__ __launch_bounds__(1024, 4) void flash_kernel(const unsigned short* __restrict__ qb,
                                                        const unsigned short* __restrict__ kb,
                                                        const unsigned short* __restrict__ ktb,
                                                        float* __restrict__ out) {
    const int h = blockIdx.x & 1;           // row half (16 rows)
    const int p = (blockIdx.x >> 1) & 31;   // pair index: tiles p and 63-p
    const int b = blockIdx.x >> 6;          // batch

    const int qtA = p, qtB = 63 - p;
    const int q0A = qtA * 32, q0B = qtB * 32;

    __shared__ __align__(16) float Ored[2][16][68];             // 8.5 KB (pad 68)
    __shared__ float lred[2][16];

    const int tid  = threadIdx.x;
    const int wv   = tid >> 6;              // 0..15
    const int lane = tid & 63;
    const int col  = lane & 15;
    const int quad = lane >> 4;

    // ---- zero the reduction buffers ----
    {
        float* z = &Ored[0][0][0];
        for (int i = tid; i < 2 * 16 * 68; i += 1024) z[i] = 0.f;
        if (tid < 32) lred[tid >> 4][tid & 15] = 0.f;
    }
    __syncthreads();

    const unsigned short* kp  = kb  + (size_t)b * TT * DH;
    const unsigned short* ktp = ktb + (size_t)b * 64 * TT;
    const int qrowA = q0A + h * 16, qrowB = q0B + h * 16;
    const unsigned short* qpA = qb + ((size_t)b * TT + qrowA) * DH;
    const unsigned short* qpB = qb + ((size_t)b * TT + qrowB) * DH;

    // Q B-frags for both tiles (col=lane&15 = q-row, k = quad*8+j; pre-scaled)
    short8 qfA0 = *reinterpret_cast<const short8*>(qpA + (size_t)col * DH + quad * 8);
    short8 qfA1 = *reinterpret_cast<const short8*>(qpA + (size_t)col * DH + 32 + quad * 8);
    short8 qfB0 = *reinterpret_cast<const short8*>(qpB + (size_t)col * DH + quad * 8);
    short8 qfB1 = *reinterpret_cast<const short8*>(qpB + (size_t)col * DH + 32 + quad * 8);

    // Wave's contiguous slice of the 65-body list: [w0, w1)
    const int w0 = (65 * wv) >> 4;
    const int w1 = (65 * (wv + 1)) >> 4;

    floatx4 oA[4], oB[4];
#pragma unroll
    for (int t = 0; t < 4; ++t) { oA[t] = (floatx4){0.f,0.f,0.f,0.f}; oB[t] = (floatx4){0.f,0.f,0.f,0.f}; }
    float lsumA = 0.f, lsumB = 0.f;

    // K A-frag key for subtile st: a-row = lane&15 -> key s0 + ((a>>2))*8 + st*4 + (a&3)
    const int koff0 = ((lane >> 2) & 3) * 8 + (lane & 3);   // st=0 key offset

    auto body = [&](int s0, bool domask, const short8& qf0, const short8& qf1,
                    int qrow, floatx4* o, float& lsum) {
        const int qglob = qrow + col;       // this lane's q-row (D-col = lane&15)
        float sv[2][4];
#pragma unroll
        for (int st = 0; st < 2; ++st) {
            const int skey = s0 + koff0 + st * 4;
            const unsigned short* kr = kp + (size_t)skey * DH + quad * 8;
            short8 kf0 = *reinterpret_cast<const short8*>(kr);
            short8 kf1 = *reinterpret_cast<const short8*>(kr + 32);
            floatx4 z = (floatx4){0.f, 0.f, 0.f, 0.f};
            z = __builtin_amdgcn_mfma_f32_16x16x32_bf16(kf0, qf0, z, 0, 0, 0);
            z = __builtin_amdgcn_mfma_f32_16x16x32_bf16(kf1, qf1, z, 0, 0, 0);
            const int kbase = s0 + quad * 8 + st * 4;   // this lane's key base (D-row)
#pragma unroll
            for (int r = 0; r < 4; ++r) {
                float pv = __builtin_exp2f(z[r]);              // log2e pre-folded into Q
                if (domask) pv = (kbase + r <= qglob) ? pv : 0.f;
                sv[st][r] = pv;
                lsum += pv;
            }
        }
        // P is lane-local: pack keys quad*8+{0..7} for PV's A-frag (no LDS!)
        union { unsigned int u[4]; short8 s; } pa;
        pa.u[0] = cvtpk(sv[0][0], sv[0][1]);
        pa.u[1] = cvtpk(sv[0][2], sv[0][3]);
        pa.u[2] = cvtpk(sv[1][0], sv[1][1]);
        pa.u[3] = cvtpk(sv[1][2], sv[1][3]);

        // O += P V  (V == K), B-frags from global kt [d][s], keys s0+quad*8+j
#pragma unroll
        for (int t = 0; t < 4; ++t) {
            short8 vf = *reinterpret_cast<const short8*>(
                ktp + (size_t)(t * 16 + col) * TT + s0 + quad * 8);
            o[t] = __builtin_amdgcn_mfma_f32_16x16x32_bf16(pa.s, vf, o[t], 0, 0, 0);
        }
    };

    // ---- tile-A bodies: j in [w0, min(w1, p+1)), s0 = 32j, diag at j == qtA ----
    const int a_end = min(w1, p + 1);
    for (int j = w0; j < a_end; ++j)
        body(32 * j, j == qtA, qfA0, qfA1, qrowA, oA, lsumA);

    // ---- tile-B bodies: j in [max(w0, p+1), w1), i = j-p-1, diag at i == qtB ----
    const int b_beg = max(w0, p + 1);
    for (int j = b_beg; j < w1; ++j) {
        const int i = j - p - 1;
        body(32 * i, i == qtB, qfB0, qfB1, qrowB, oB, lsumB);
    }

    // ---- reduce l across the 4 quads holding each q-row's keys ----
    lsumA += __shfl_xor(lsumA, 16, 64);
    lsumA += __shfl_xor(lsumA, 32, 64);
    lsumB += __shfl_xor(lsumB, 16, 64);
    lsumB += __shfl_xor(lsumB, 32, 64);

    // ---- deposit partials via LDS atomics (ds_add_f32, no return) ----
    if (w0 < p + 1) {                       // wave touched tile A
#pragma unroll
        for (int t = 0; t < 4; ++t)
#pragma unroll
            for (int r = 0; r < 4; ++r)
                atomicAdd(&Ored[0][quad * 4 + r][t * 16 + col], oA[t][r]);
        if (lane < 16) atomicAdd(&lred[0][lane], lsumA);
    }
    if (w1 > p + 1) {                       // wave touched tile B
#pragma unroll
        for (int t = 0; t < 4; ++t)
#pragma unroll
            for (int r = 0; r < 4; ++r)
                atomicAdd(&Ored[1][quad * 4 + r][t * 16 + col], oB[t][r]);
        if (lane < 16) atomicAdd(&lred[1][lane], lsumB);
    }
    __syncthreads();

    // ---- merge: thread owns (tile, row, 4-col group); write fp32 out ----
    if (tid < 512) {
        const int tile = tid >> 8;          // 0..1
        const int row  = (tid >> 4) & 15;   // 0..15
        const int c4   = (tid & 15) * 4;    // 0..60
        const float inv = 1.0f / lred[tile][row];
        const int grow = (tile == 0 ? qrowA : qrowB) + row;
        float4 r = {Ored[tile][row][c4 + 0] * inv, Ored[tile][row][c4 + 1] * inv,
                    Ored[tile][row][c4 + 2] * inv, Ored[tile][row][c4 + 3] * inv};
        *reinterpret_cast<float4*>(out + ((size_t)b * TT + grow) * DH + c4) = r;
    }
}

// ---------------------------------------------------------------------------
extern "C" void kernel_launch(void* const* d_in, const int* in_sizes, int n_in,
                              void* d_out, int out_size, void* d_ws, size_t ws_size,
                              hipStream_t stream) {
    const float* x  = (const float*)d_in[0];
    const float* wq = (const float*)d_in[1];
    const float* wk = (const float*)d_in[2];
    // d_in[3] (W_V) is unused — faithful to the reference's source bug.

    unsigned short* wbt = (unsigned short*)d_ws;          // [8][32][64][8] bf16 tiled W
    unsigned short* qo  = wbt + (size_t)WTHREADS * 8;     // [8192][64] bf16 (pre-scaled)
    unsigned short* ko  = qo + (size_t)BB * TT * DH;      // [8192][64] bf16
    unsigned short* kt  = ko + (size_t)BB * TT * DH;      // [4][64][2048] bf16 (K^T)
    float* out = (float*)d_out;

    hipLaunchKernelGGL(wtile_kernel, dim3(WTHREADS / 256), dim3(256), 0, stream, wq, wk, wbt);
    hipLaunchKernelGGL(proj_kernel,  dim3((BB * TT) / 16), dim3(256), 0, stream, x, wbt, qo, ko, kt);
    hipLaunchKernelGGL(flash_kernel, dim3(BB * 64),        dim3(1024), 0, stream, qo, ko, kt, out);
}

// Round 8
// 123.308 us; speedup vs baseline: 1.0204x; 1.0204x over previous
//
#include <hip/hip_runtime.h>
#include <hip/hip_bf16.h>
#include <cstdint>
#include <cstddef>

// Problem constants (fixed by the reference setup)
#define BB 4
#define TT 2048
#define DM 1024
#define DH 64

typedef __attribute__((ext_vector_type(8))) short short8;   // 8 bf16 (4 VGPRs)
typedef __attribute__((ext_vector_type(4))) float floatx4;  // MFMA C/D

__device__ __forceinline__ unsigned short f2bf(float f) {
    union { float f; unsigned int u; } v; v.f = f;
    unsigned int u = v.u;
    u += 0x7fffu + ((u >> 16) & 1u);   // RNE; inputs are finite
    return (unsigned short)(u >> 16);
}

__device__ __forceinline__ float bf2f(unsigned short h) {
    union { unsigned int u; float f; } v;
    v.u = ((unsigned int)h) << 16;
    return v.f;
}

// HW packed f32->bf16 (RNE), 1 VALU op for 2 values. Non-volatile: scheduler-free.
__device__ __forceinline__ unsigned int cvtpk(float a, float b) {
    unsigned int r;
    asm("v_cvt_pk_bf16_f32 %0, %1, %2" : "=v"(r) : "v"(a), "v"(b));
    return r;
}

__device__ __forceinline__ short8 cvt8(float4 lo, float4 hi) {
    union { unsigned int u[4]; short8 s; } v;
    v.u[0] = cvtpk(lo.x, lo.y);
    v.u[1] = cvtpk(lo.z, lo.w);
    v.u[2] = cvtpk(hi.x, hi.y);
    v.u[3] = cvtpk(hi.z, hi.w);
    return v.s;
}

// ---------------------------------------------------------------------------
// Kernel 0: pre-tile W_Q/W_K into B-frag order (tiny: 512 KB out).
//   wbt[nt][kc][lane][8] = W[(nt&3)*16 + (lane&15)][kc*32 + (lane>>4)*8 + j]
//   nt 0-3 = W_Q, nt 4-7 = W_K.
// ---------------------------------------------------------------------------
#define WTHREADS (8 * 32 * 64)       // 16384: 64 blocks

__global__ __launch_bounds__(256) void wtile_kernel(const float* __restrict__ wq,
                                                    const float* __restrict__ wk,
                                                    unsigned short* __restrict__ wbt) {
    const int j  = blockIdx.x * 256 + threadIdx.x;   // 0..16383
    const int l  = j & 63;
    const int kc = (j >> 6) & 31;
    const int nt = j >> 11;                          // 0..7
    const float* wbase = (nt < 4) ? wq : wk;
    const float* src = wbase + (size_t)((nt & 3) * 16 + (l & 15)) * DM
                             + kc * 32 + (l >> 4) * 8;
    float4 a = *reinterpret_cast<const float4*>(src);
    float4 b = *reinterpret_cast<const float4*>(src + 4);
    *reinterpret_cast<short8*>(wbt + (size_t)j * 8) = cvt8(a, b);
}

// ---------------------------------------------------------------------------
// Kernel 1: fused convert + projection GEMM (2-half pipeline). 512 blocks x
// 4 waves; block owns one 16-row m-tile. Wave w: Q n-tile w, K n-tile 4+w.
// Q is pre-scaled by (1/sqrt(1024)) * log2(e) so flash can use exp2 directly.
// ---------------------------------------------------------------------------
__global__ __launch_bounds__(256) void proj_kernel(const float* __restrict__ x,
                                                   const unsigned short* __restrict__ wbt,
                                                   unsigned short* __restrict__ qo,
                                                   unsigned short* __restrict__ ko,
                                                   unsigned short* __restrict__ kt) {
    __shared__ __align__(16) unsigned short sA[2][16 * 64 * 8];  // 2 x 16 KB halves

    const int tid  = threadIdx.x;
    const int wave = tid >> 6;
    const int lane = tid & 63;
    const int col  = lane & 15;
    const int quad = lane >> 4;
    const int mt   = blockIdx.x;

    const float* xtile = x + (size_t)mt * 16 * DM;
    const unsigned short* bq = wbt + ((size_t)wave * 32 * 64) * 8;
    const unsigned short* bk = wbt + ((size_t)(4 + wave) * 32 * 64) * 8;

    floatx4 accQ = (floatx4){0.f, 0.f, 0.f, 0.f};
    floatx4 accK = (floatx4){0.f, 0.f, 0.f, 0.f};

    // ---- stage half 0 (kc 0..15) ----
#pragma unroll 4
    for (int i = 0; i < 4; ++i) {
        const int e  = tid + i * 256;          // 0..1023
        const int kc = e >> 6;
        const int l  = e & 63;
        const float* src = xtile + (size_t)(l & 15) * DM + kc * 32 + (l >> 4) * 8;
        float4 a = *reinterpret_cast<const float4*>(src);
        float4 b = *reinterpret_cast<const float4*>(src + 4);
        *reinterpret_cast<short8*>(sA[0] + (size_t)e * 8) = cvt8(a, b);
    }
    __syncthreads();

    // ---- issue half-1 loads (kc 16..31) BEFORE computing half 0 ----
    float4 h1a[4], h1b[4];
#pragma unroll 4
    for (int i = 0; i < 4; ++i) {
        const int e  = tid + i * 256;
        const int kc = 16 + (e >> 6);
        const int l  = e & 63;
        const float* src = xtile + (size_t)(l & 15) * DM + kc * 32 + (l >> 4) * 8;
        h1a[i] = *reinterpret_cast<const float4*>(src);
        h1b[i] = *reinterpret_cast<const float4*>(src + 4);
    }

    // ---- compute half 0 while half-1 loads are in flight ----
#pragma unroll
    for (int kc = 0; kc < 16; ++kc) {
        short8 a  = *reinterpret_cast<const short8*>(sA[0] + ((size_t)kc * 64 + lane) * 8);
        short8 b0 = *reinterpret_cast<const short8*>(bq + ((size_t)kc * 64 + lane) * 8);
        short8 b1 = *reinterpret_cast<const short8*>(bk + ((size_t)kc * 64 + lane) * 8);
        accQ = __builtin_amdgcn_mfma_f32_16x16x32_bf16(a, b0, accQ, 0, 0, 0);
        accK = __builtin_amdgcn_mfma_f32_16x16x32_bf16(a, b1, accK, 0, 0, 0);
    }

    // ---- write half 1 (separate buffer: no barrier needed before writes) ----
#pragma unroll 4
    for (int i = 0; i < 4; ++i) {
        const int e = tid + i * 256;
        *reinterpret_cast<short8*>(sA[1] + (size_t)e * 8) = cvt8(h1a[i], h1b[i]);
    }
    __syncthreads();

    // ---- compute half 1 ----
#pragma unroll
    for (int kc = 0; kc < 16; ++kc) {
        short8 a  = *reinterpret_cast<const short8*>(sA[1] + ((size_t)kc * 64 + lane) * 8);
        short8 b0 = *reinterpret_cast<const short8*>(bq + ((size_t)(16 + kc) * 64 + lane) * 8);
        short8 b1 = *reinterpret_cast<const short8*>(bk + ((size_t)(16 + kc) * 64 + lane) * 8);
        accQ = __builtin_amdgcn_mfma_f32_16x16x32_bf16(a, b0, accQ, 0, 0, 0);
        accK = __builtin_amdgcn_mfma_f32_16x16x32_bf16(a, b1, accK, 0, 0, 0);
    }

    // ---- epilogue: C/D layout col = lane&15, row = quad*4 + r ----
    // Q scale folds in log2(e): 1/32 * 1.44269504 = 0.04508422
    const int g = wave * 16 + col;             // output col 0..63
    unsigned short hk[4];
#pragma unroll
    for (int r = 0; r < 4; ++r) {
        const size_t row = (size_t)(mt * 16 + quad * 4 + r);
        qo[row * DH + g] = f2bf(accQ[r] * 0.04508422f);
        hk[r] = f2bf(accK[r]);
        ko[row * DH + g] = hk[r];
    }

    // ---- kt: transpose K tile through LDS (reuse sA), write 32B runs ----
    __syncthreads();                           // all waves done reading sA
    unsigned short* kts = (unsigned short*)sA; // [64 d][16 s] shorts, 2 KB
#pragma unroll
    for (int r = 0; r < 4; ++r)
        kts[g * 16 + quad * 4 + r] = hk[r];
    __syncthreads();
    if (tid < 128) {
        const int d  = tid >> 1;
        const int s8 = (tid & 1) * 8;
        const int b4 = mt >> 7;                       // batch
        const int s0 = (mt & 127) * 16 + s8;          // seq pos within batch
        short8 v = *reinterpret_cast<const short8*>(kts + d * 16 + s8);
        *reinterpret_cast<short8*>(kt + ((size_t)(b4 * 64 + d)) * TT + s0) = v;
    }
}

// ---------------------------------------------------------------------------
// Kernel 2: FUSED flash + merge, PAIR-BALANCED, IN-REGISTER SOFTMAX,
// 16 waves/block with PHASE-SPLIT register lifetimes: process tile A ->
// deposit -> process tile B -> deposit. Only ONE o[4] accumulator set and
// ONE Q-frag pair live at a time (~80-100 VGPR), so the (1024,4) bound
// (VGPR<=128, 4 waves/SIMD) holds WITHOUT spills — this deconfounds the
// R7 TLP experiment (which spilled: both tiles' state live under the cap).
// Swapped QK^T keeps P lane-local. LDS-atomic merge as before.
// ---------------------------------------------------------------------------
__global__ __launch_bounds__(1024, 4) void flash_kernel(const unsigned short* __restrict__ qb,
                                                        const unsigned short* __restrict__ kb,
                                                        const unsigned short* __restrict__ ktb,
                                                        float* __restrict__ out) {
    const int h = blockIdx.x & 1;           // row half (16 rows)
    const int p = (blockIdx.x >> 1) & 31;   // pair index: tiles p and 63-p
    const int b = blockIdx.x >> 6;          // batch

    const int qtA = p, qtB = 63 - p;
    const int q0A = qtA * 32, q0B = qtB * 32;

    __shared__ __align__(16) float Ored[2][16][68];             // 8.5 KB (pad 68)
    __shared__ float lred[2][16];

    const int tid  = threadIdx.x;
    const int wv   = tid >> 6;              // 0..15
    const int lane = tid & 63;
    const int col  = lane & 15;
    const int quad = lane >> 4;

    // ---- zero the reduction buffers ----
    {
        float* z = &Ored[0][0][0];
        for (int i = tid; i < 2 * 16 * 68; i += 1024) z[i] = 0.f;
        if (tid < 32) lred[tid >> 4][tid & 15] = 0.f;
    }
    __syncthreads();

    const unsigned short* kp  = kb  + (size_t)b * TT * DH;
    const unsigned short* ktp = ktb + (size_t)b * 64 * TT;
    const int qrowA = q0A + h * 16, qrowB = q0B + h * 16;

    // Wave's contiguous slice of the 65-body list: [w0, w1)
    const int w0 = (65 * wv) >> 4;
    const int w1 = (65 * (wv + 1)) >> 4;

    // K A-frag key for subtile st: a-row = lane&15 -> key s0 + ((a>>2))*8 + st*4 + (a&3)
    const int koff0 = ((lane >> 2) & 3) * 8 + (lane & 3);   // st=0 key offset

    // Phase runner: loads Q frags, processes bodies [j0,j1) (s0 = 32*(j - jofs)),
    // deposits o + lsum via LDS atomics. All state local to the call -> short
    // register lifetimes; A and B phases never coexist.
    auto phase = [&](int j0, int j1, int jofs, int qtile, int qrow, int slot) {
        if (j0 >= j1) return;
        const unsigned short* qp = qb + ((size_t)b * TT + qrow) * DH;
        short8 qf0 = *reinterpret_cast<const short8*>(qp + (size_t)col * DH + quad * 8);
        short8 qf1 = *reinterpret_cast<const short8*>(qp + (size_t)col * DH + 32 + quad * 8);

        floatx4 o[4];
#pragma unroll
        for (int t = 0; t < 4; ++t) o[t] = (floatx4){0.f, 0.f, 0.f, 0.f};
        float lsum = 0.f;
        const int qglob = qrow + col;       // this lane's q-row (D-col = lane&15)

        for (int j = j0; j < j1; ++j) {
            const int i  = j - jofs;        // body index within tile
            const int s0 = 32 * i;
            const bool domask = (i == qtile);
            float sv[2][4];
#pragma unroll
            for (int st = 0; st < 2; ++st) {
                const int skey = s0 + koff0 + st * 4;
                const unsigned short* kr = kp + (size_t)skey * DH + quad * 8;
                short8 kf0 = *reinterpret_cast<const short8*>(kr);
                short8 kf1 = *reinterpret_cast<const short8*>(kr + 32);
                floatx4 z = (floatx4){0.f, 0.f, 0.f, 0.f};
                z = __builtin_amdgcn_mfma_f32_16x16x32_bf16(kf0, qf0, z, 0, 0, 0);
                z = __builtin_amdgcn_mfma_f32_16x16x32_bf16(kf1, qf1, z, 0, 0, 0);
                const int kbase = s0 + quad * 8 + st * 4;   // lane's key base (D-row)
#pragma unroll
                for (int r = 0; r < 4; ++r) {
                    float pv = __builtin_exp2f(z[r]);           // log2e pre-folded into Q
                    if (domask) pv = (kbase + r <= qglob) ? pv : 0.f;
                    sv[st][r] = pv;
                    lsum += pv;
                }
            }
            // P is lane-local: pack keys quad*8+{0..7} for PV's A-frag (no LDS!)
            union { unsigned int u[4]; short8 s; } pa;
            pa.u[0] = cvtpk(sv[0][0], sv[0][1]);
            pa.u[1] = cvtpk(sv[0][2], sv[0][3]);
            pa.u[2] = cvtpk(sv[1][0], sv[1][1]);
            pa.u[3] = cvtpk(sv[1][2], sv[1][3]);

            // O += P V  (V == K), B-frags from global kt [d][s], keys s0+quad*8+j
#pragma unroll
            for (int t = 0; t < 4; ++t) {
                short8 vf = *reinterpret_cast<const short8*>(
                    ktp + (size_t)(t * 16 + col) * TT + s0 + quad * 8);
                o[t] = __builtin_amdgcn_mfma_f32_16x16x32_bf16(pa.s, vf, o[t], 0, 0, 0);
            }
        }

        // reduce l across the 4 quads holding each q-row's keys
        lsum += __shfl_xor(lsum, 16, 64);
        lsum += __shfl_xor(lsum, 32, 64);

        // deposit partials via LDS atomics (ds_add_f32, no return)
#pragma unroll
        for (int t = 0; t < 4; ++t)
#pragma unroll
            for (int r = 0; r < 4; ++r)
                atomicAdd(&Ored[slot][quad * 4 + r][t * 16 + col], o[t][r]);
        if (lane < 16) atomicAdd(&lred[slot][lane], lsum);
    };

    // ---- phase A: bodies [w0, min(w1, p+1)), tile qtA; then phase B ----
    phase(w0, min(w1, p + 1), 0,     qtA, qrowA, 0);
    phase(max(w0, p + 1), w1, p + 1, qtB, qrowB, 1);

    __syncthreads();

    // ---- merge: thread owns (tile, row, 4-col group); write fp32 out ----
    if (tid < 512) {
        const int tile = tid >> 8;          // 0..1
        const int row  = (tid >> 4) & 15;   // 0..15
        const int c4   = (tid & 15) * 4;    // 0..60
        const float inv = 1.0f / lred[tile][row];
        const int grow = (tile == 0 ? qrowA : qrowB) + row;
        float4 r = {Ored[tile][row][c4 + 0] * inv, Ored[tile][row][c4 + 1] * inv,
                    Ored[tile][row][c4 + 2] * inv, Ored[tile][row][c4 + 3] * inv};
        *reinterpret_cast<float4*>(out + ((size_t)b * TT + grow) * DH + c4) = r;
    }
}

// ---------------------------------------------------------------------------
extern "C" void kernel_launch(void* const* d_in, const int* in_sizes, int n_in,
                              void* d_out, int out_size, void* d_ws, size_t ws_size,
                              hipStream_t stream) {
    const float* x  = (const float*)d_in[0];
    const float* wq = (const float*)d_in[1];
    const float* wk = (const float*)d_in[2];
    // d_in[3] (W_V) is unused — faithful to the reference's source bug.

    unsigned short* wbt = (unsigned short*)d_ws;          // [8][32][64][8] bf16 tiled W
    unsigned short* qo  = wbt + (size_t)WTHREADS * 8;     // [8192][64] bf16 (pre-scaled)
    unsigned short* ko  = qo + (size_t)BB * TT * DH;      // [8192][64] bf16
    unsigned short* kt  = ko + (size_t)BB * TT * DH;      // [4][64][2048] bf16 (K^T)
    float* out = (float*)d_out;

    hipLaunchKernelGGL(wtile_kernel, dim3(WTHREADS / 256), dim3(256), 0, stream, wq, wk, wbt);
    hipLaunchKernelGGL(proj_kernel,  dim3((BB * TT) / 16), dim3(256), 0, stream, x, wbt, qo, ko, kt);
    hipLaunchKernelGGL(flash_kernel, dim3(BB * 64),        dim3(1024), 0, stream, qo, ko, kt, out);
}

// Round 9
// 116.003 us; speedup vs baseline: 1.0847x; 1.0630x over previous
//
#include <hip/hip_runtime.h>
#include <hip/hip_bf16.h>
#include <cstdint>
#include <cstddef>

// Problem constants (fixed by the reference setup)
#define BB 4
#define TT 2048
#define DM 1024
#define DH 64

typedef __attribute__((ext_vector_type(8))) short short8;   // 8 bf16 (4 VGPRs)
typedef __attribute__((ext_vector_type(4))) float floatx4;  // MFMA C/D

__device__ __forceinline__ unsigned short f2bf(float f) {
    union { float f; unsigned int u; } v; v.f = f;
    unsigned int u = v.u;
    u += 0x7fffu + ((u >> 16) & 1u);   // RNE; inputs are finite
    return (unsigned short)(u >> 16);
}

__device__ __forceinline__ float bf2f(unsigned short h) {
    union { unsigned int u; float f; } v;
    v.u = ((unsigned int)h) << 16;
    return v.f;
}

// HW packed f32->bf16 (RNE), 1 VALU op for 2 values. Non-volatile: scheduler-free.
__device__ __forceinline__ unsigned int cvtpk(float a, float b) {
    unsigned int r;
    asm("v_cvt_pk_bf16_f32 %0, %1, %2" : "=v"(r) : "v"(a), "v"(b));
    return r;
}

__device__ __forceinline__ short8 cvt8(float4 lo, float4 hi) {
    union { unsigned int u[4]; short8 s; } v;
    v.u[0] = cvtpk(lo.x, lo.y);
    v.u[1] = cvtpk(lo.z, lo.w);
    v.u[2] = cvtpk(hi.x, hi.y);
    v.u[3] = cvtpk(hi.z, hi.w);
    return v.s;
}

// ---------------------------------------------------------------------------
// Kernel 0: pre-tile W_Q/W_K into B-frag order (tiny: 512 KB out).
//   wbt[nt][kc][lane][8] = W[(nt&3)*16 + (lane&15)][kc*32 + (lane>>4)*8 + j]
//   nt 0-3 = W_Q, nt 4-7 = W_K.
// ---------------------------------------------------------------------------
#define WTHREADS (8 * 32 * 64)       // 16384: 64 blocks

__global__ __launch_bounds__(256) void wtile_kernel(const float* __restrict__ wq,
                                                    const float* __restrict__ wk,
                                                    unsigned short* __restrict__ wbt) {
    const int j  = blockIdx.x * 256 + threadIdx.x;   // 0..16383
    const int l  = j & 63;
    const int kc = (j >> 6) & 31;
    const int nt = j >> 11;                          // 0..7
    const float* wbase = (nt < 4) ? wq : wk;
    const float* src = wbase + (size_t)((nt & 3) * 16 + (l & 15)) * DM
                             + kc * 32 + (l >> 4) * 8;
    float4 a = *reinterpret_cast<const float4*>(src);
    float4 b = *reinterpret_cast<const float4*>(src + 4);
    *reinterpret_cast<short8*>(wbt + (size_t)j * 8) = cvt8(a, b);
}

// ---------------------------------------------------------------------------
// Kernel 1: fused convert + projection GEMM (2-half pipeline). 512 blocks x
// 4 waves; block owns one 16-row m-tile. Wave w: Q n-tile w, K n-tile 4+w.
// Q is pre-scaled by (1/sqrt(1024)) * log2(e) so flash can use exp2 directly.
// ---------------------------------------------------------------------------
__global__ __launch_bounds__(256) void proj_kernel(const float* __restrict__ x,
                                                   const unsigned short* __restrict__ wbt,
                                                   unsigned short* __restrict__ qo,
                                                   unsigned short* __restrict__ ko,
                                                   unsigned short* __restrict__ kt) {
    __shared__ __align__(16) unsigned short sA[2][16 * 64 * 8];  // 2 x 16 KB halves

    const int tid  = threadIdx.x;
    const int wave = tid >> 6;
    const int lane = tid & 63;
    const int col  = lane & 15;
    const int quad = lane >> 4;
    const int mt   = blockIdx.x;

    const float* xtile = x + (size_t)mt * 16 * DM;
    const unsigned short* bq = wbt + ((size_t)wave * 32 * 64) * 8;
    const unsigned short* bk = wbt + ((size_t)(4 + wave) * 32 * 64) * 8;

    floatx4 accQ = (floatx4){0.f, 0.f, 0.f, 0.f};
    floatx4 accK = (floatx4){0.f, 0.f, 0.f, 0.f};

    // ---- stage half 0 (kc 0..15) ----
#pragma unroll 4
    for (int i = 0; i < 4; ++i) {
        const int e  = tid + i * 256;          // 0..1023
        const int kc = e >> 6;
        const int l  = e & 63;
        const float* src = xtile + (size_t)(l & 15) * DM + kc * 32 + (l >> 4) * 8;
        float4 a = *reinterpret_cast<const float4*>(src);
        float4 b = *reinterpret_cast<const float4*>(src + 4);
        *reinterpret_cast<short8*>(sA[0] + (size_t)e * 8) = cvt8(a, b);
    }
    __syncthreads();

    // ---- issue half-1 loads (kc 16..31) BEFORE computing half 0 ----
    float4 h1a[4], h1b[4];
#pragma unroll 4
    for (int i = 0; i < 4; ++i) {
        const int e  = tid + i * 256;
        const int kc = 16 + (e >> 6);
        const int l  = e & 63;
        const float* src = xtile + (size_t)(l & 15) * DM + kc * 32 + (l >> 4) * 8;
        h1a[i] = *reinterpret_cast<const float4*>(src);
        h1b[i] = *reinterpret_cast<const float4*>(src + 4);
    }

    // ---- compute half 0 while half-1 loads are in flight ----
#pragma unroll
    for (int kc = 0; kc < 16; ++kc) {
        short8 a  = *reinterpret_cast<const short8*>(sA[0] + ((size_t)kc * 64 + lane) * 8);
        short8 b0 = *reinterpret_cast<const short8*>(bq + ((size_t)kc * 64 + lane) * 8);
        short8 b1 = *reinterpret_cast<const short8*>(bk + ((size_t)kc * 64 + lane) * 8);
        accQ = __builtin_amdgcn_mfma_f32_16x16x32_bf16(a, b0, accQ, 0, 0, 0);
        accK = __builtin_amdgcn_mfma_f32_16x16x32_bf16(a, b1, accK, 0, 0, 0);
    }

    // ---- write half 1 (separate buffer: no barrier needed before writes) ----
#pragma unroll 4
    for (int i = 0; i < 4; ++i) {
        const int e = tid + i * 256;
        *reinterpret_cast<short8*>(sA[1] + (size_t)e * 8) = cvt8(h1a[i], h1b[i]);
    }
    __syncthreads();

    // ---- compute half 1 ----
#pragma unroll
    for (int kc = 0; kc < 16; ++kc) {
        short8 a  = *reinterpret_cast<const short8*>(sA[1] + ((size_t)kc * 64 + lane) * 8);
        short8 b0 = *reinterpret_cast<const short8*>(bq + ((size_t)(16 + kc) * 64 + lane) * 8);
        short8 b1 = *reinterpret_cast<const short8*>(bk + ((size_t)(16 + kc) * 64 + lane) * 8);
        accQ = __builtin_amdgcn_mfma_f32_16x16x32_bf16(a, b0, accQ, 0, 0, 0);
        accK = __builtin_amdgcn_mfma_f32_16x16x32_bf16(a, b1, accK, 0, 0, 0);
    }

    // ---- epilogue: C/D layout col = lane&15, row = quad*4 + r ----
    // Q scale folds in log2(e): 1/32 * 1.44269504 = 0.04508422
    const int g = wave * 16 + col;             // output col 0..63
    unsigned short hk[4];
#pragma unroll
    for (int r = 0; r < 4; ++r) {
        const size_t row = (size_t)(mt * 16 + quad * 4 + r);
        qo[row * DH + g] = f2bf(accQ[r] * 0.04508422f);
        hk[r] = f2bf(accK[r]);
        ko[row * DH + g] = hk[r];
    }

    // ---- kt: transpose K tile through LDS (reuse sA), write 32B runs ----
    __syncthreads();                           // all waves done reading sA
    unsigned short* kts = (unsigned short*)sA; // [64 d][16 s] shorts, 2 KB
#pragma unroll
    for (int r = 0; r < 4; ++r)
        kts[g * 16 + quad * 4 + r] = hk[r];
    __syncthreads();
    if (tid < 128) {
        const int d  = tid >> 1;
        const int s8 = (tid & 1) * 8;
        const int b4 = mt >> 7;                       // batch
        const int s0 = (mt & 127) * 16 + s8;          // seq pos within batch
        short8 v = *reinterpret_cast<const short8*>(kts + d * 16 + s8);
        *reinterpret_cast<short8*>(kt + ((size_t)(b4 * 64 + d)) * TT + s0) = v;
    }
}

// ---------------------------------------------------------------------------
// Kernel 2: FUSED flash + merge, PAIR-BALANCED, IN-REGISTER SOFTMAX.
// Swapped QK^T: z = mfma(K_frag, Q_frag) puts q-row in lane&15 and the key
// in (quad*4+r). Key bijection key = s0 + (a>>2)*8 + st*4 + (a&3) makes each
// lane hold exactly keys quad*8+{0..7} -> P feeds PV's A-frag DIRECTLY from
// registers (4 cvt_pk; no LDS P staging, no ds round-trip in the body).
// Block = (b, pair p, half h): owns q-tiles p and 63-p -> 65 bodies/block,
// identical load on all 256 blocks. LDS-atomic merge.
// NOTE: 512 threads (2 waves/SIMD) is the measured optimum — both 1024-thread
// variants (R7 spilled, R8 phase-split spill-free) regressed 7-9 µs.
// ---------------------------------------------------------------------------
__global__ __launch_bounds__(512) void flash_kernel(const unsigned short* __restrict__ qb,
                                                    const unsigned short* __restrict__ kb,
                                                    const unsigned short* __restrict__ ktb,
                                                    float* __restrict__ out) {
    const int h = blockIdx.x & 1;           // row half (16 rows)
    const int p = (blockIdx.x >> 1) & 31;   // pair index: tiles p and 63-p
    const int b = blockIdx.x >> 6;          // batch

    const int qtA = p, qtB = 63 - p;
    const int q0A = qtA * 32, q0B = qtB * 32;

    __shared__ __align__(16) float Ored[2][16][68];             // 8.5 KB (pad 68)
    __shared__ float lred[2][16];

    const int tid  = threadIdx.x;
    const int wv   = tid >> 6;              // 0..7
    const int lane = tid & 63;
    const int col  = lane & 15;
    const int quad = lane >> 4;

    // ---- zero the reduction buffers ----
    {
        float* z = &Ored[0][0][0];
        for (int i = tid; i < 2 * 16 * 68; i += 512) z[i] = 0.f;
        if (tid < 32) lred[tid >> 4][tid & 15] = 0.f;
    }
    __syncthreads();

    const unsigned short* kp  = kb  + (size_t)b * TT * DH;
    const unsigned short* ktp = ktb + (size_t)b * 64 * TT;
    const int qrowA = q0A + h * 16, qrowB = q0B + h * 16;
    const unsigned short* qpA = qb + ((size_t)b * TT + qrowA) * DH;
    const unsigned short* qpB = qb + ((size_t)b * TT + qrowB) * DH;

    // Q B-frags for both tiles (col=lane&15 = q-row, k = quad*8+j; pre-scaled)
    short8 qfA0 = *reinterpret_cast<const short8*>(qpA + (size_t)col * DH + quad * 8);
    short8 qfA1 = *reinterpret_cast<const short8*>(qpA + (size_t)col * DH + 32 + quad * 8);
    short8 qfB0 = *reinterpret_cast<const short8*>(qpB + (size_t)col * DH + quad * 8);
    short8 qfB1 = *reinterpret_cast<const short8*>(qpB + (size_t)col * DH + 32 + quad * 8);

    // Wave's contiguous slice of the 65-body list: [w0, w1)
    const int w0 = (65 * wv) >> 3;
    const int w1 = (65 * (wv + 1)) >> 3;

    floatx4 oA[4], oB[4];
#pragma unroll
    for (int t = 0; t < 4; ++t) { oA[t] = (floatx4){0.f,0.f,0.f,0.f}; oB[t] = (floatx4){0.f,0.f,0.f,0.f}; }
    float lsumA = 0.f, lsumB = 0.f;

    // K A-frag key for subtile st: a-row = lane&15 -> key s0 + ((a>>2))*8 + st*4 + (a&3)
    const int koff0 = ((lane >> 2) & 3) * 8 + (lane & 3);   // st=0 key offset

    auto body = [&](int s0, bool domask, const short8& qf0, const short8& qf1,
                    int qrow, floatx4* o, float& lsum) {
        const int qglob = qrow + col;       // this lane's q-row (D-col = lane&15)
        float sv[2][4];
#pragma unroll
        for (int st = 0; st < 2; ++st) {
            const int skey = s0 + koff0 + st * 4;
            const unsigned short* kr = kp + (size_t)skey * DH + quad * 8;
            short8 kf0 = *reinterpret_cast<const short8*>(kr);
            short8 kf1 = *reinterpret_cast<const short8*>(kr + 32);
            floatx4 z = (floatx4){0.f, 0.f, 0.f, 0.f};
            z = __builtin_amdgcn_mfma_f32_16x16x32_bf16(kf0, qf0, z, 0, 0, 0);
            z = __builtin_amdgcn_mfma_f32_16x16x32_bf16(kf1, qf1, z, 0, 0, 0);
            const int kbase = s0 + quad * 8 + st * 4;   // this lane's key base (D-row)
#pragma unroll
            for (int r = 0; r < 4; ++r) {
                float pv = __builtin_exp2f(z[r]);              // log2e pre-folded into Q
                if (domask) pv = (kbase + r <= qglob) ? pv : 0.f;
                sv[st][r] = pv;
                lsum += pv;
            }
        }
        // P is lane-local: pack keys quad*8+{0..7} for PV's A-frag (no LDS!)
        union { unsigned int u[4]; short8 s; } pa;
        pa.u[0] = cvtpk(sv[0][0], sv[0][1]);
        pa.u[1] = cvtpk(sv[0][2], sv[0][3]);
        pa.u[2] = cvtpk(sv[1][0], sv[1][1]);
        pa.u[3] = cvtpk(sv[1][2], sv[1][3]);

        // O += P V  (V == K), B-frags from global kt [d][s], keys s0+quad*8+j
#pragma unroll
        for (int t = 0; t < 4; ++t) {
            short8 vf = *reinterpret_cast<const short8*>(
                ktp + (size_t)(t * 16 + col) * TT + s0 + quad * 8);
            o[t] = __builtin_amdgcn_mfma_f32_16x16x32_bf16(pa.s, vf, o[t], 0, 0, 0);
        }
    };

    // ---- tile-A bodies: j in [w0, min(w1, p+1)), s0 = 32j, diag at j == qtA ----
    const int a_end = min(w1, p + 1);
    for (int j = w0; j < a_end; ++j)
        body(32 * j, j == qtA, qfA0, qfA1, qrowA, oA, lsumA);

    // ---- tile-B bodies: j in [max(w0, p+1), w1), i = j-p-1, diag at i == qtB ----
    const int b_beg = max(w0, p + 1);
    for (int j = b_beg; j < w1; ++j) {
        const int i = j - p - 1;
        body(32 * i, i == qtB, qfB0, qfB1, qrowB, oB, lsumB);
    }

    // ---- reduce l across the 4 quads holding each q-row's keys ----
    lsumA += __shfl_xor(lsumA, 16, 64);
    lsumA += __shfl_xor(lsumA, 32, 64);
    lsumB += __shfl_xor(lsumB, 16, 64);
    lsumB += __shfl_xor(lsumB, 32, 64);

    // ---- deposit partials via LDS atomics (ds_add_f32, no return) ----
    if (w0 < p + 1) {                       // wave touched tile A
#pragma unroll
        for (int t = 0; t < 4; ++t)
#pragma unroll
            for (int r = 0; r < 4; ++r)
                atomicAdd(&Ored[0][quad * 4 + r][t * 16 + col], oA[t][r]);
        if (lane < 16) atomicAdd(&lred[0][lane], lsumA);
    }
    if (w1 > p + 1) {                       // wave touched tile B
#pragma unroll
        for (int t = 0; t < 4; ++t)
#pragma unroll
            for (int r = 0; r < 4; ++r)
                atomicAdd(&Ored[1][quad * 4 + r][t * 16 + col], oB[t][r]);
        if (lane < 16) atomicAdd(&lred[1][lane], lsumB);
    }
    __syncthreads();

    // ---- merge: thread owns (tile, row, 4-col group); write fp32 out ----
    {
        const int tile = tid >> 8;          // 0..1
        const int row  = (tid >> 4) & 15;   // 0..15
        const int c4   = (tid & 15) * 4;    // 0..60
        const float inv = 1.0f / lred[tile][row];
        const int grow = (tile == 0 ? qrowA : qrowB) + row;
        float4 r = {Ored[tile][row][c4 + 0] * inv, Ored[tile][row][c4 + 1] * inv,
                    Ored[tile][row][c4 + 2] * inv, Ored[tile][row][c4 + 3] * inv};
        *reinterpret_cast<float4*>(out + ((size_t)b * TT + grow) * DH + c4) = r;
    }
}

// ---------------------------------------------------------------------------
extern "C" void kernel_launch(void* const* d_in, const int* in_sizes, int n_in,
                              void* d_out, int out_size, void* d_ws, size_t ws_size,
                              hipStream_t stream) {
    const float* x  = (const float*)d_in[0];
    const float* wq = (const float*)d_in[1];
    const float* wk = (const float*)d_in[2];
    // d_in[3] (W_V) is unused — faithful to the reference's source bug.

    unsigned short* wbt = (unsigned short*)d_ws;          // [8][32][64][8] bf16 tiled W
    unsigned short* qo  = wbt + (size_t)WTHREADS * 8;     // [8192][64] bf16 (pre-scaled)
    unsigned short* ko  = qo + (size_t)BB * TT * DH;      // [8192][64] bf16
    unsigned short* kt  = ko + (size_t)BB * TT * DH;      // [4][64][2048] bf16 (K^T)
    float* out = (float*)d_out;

    hipLaunchKernelGGL(wtile_kernel, dim3(WTHREADS / 256), dim3(256), 0, stream, wq, wk, wbt);
    hipLaunchKernelGGL(proj_kernel,  dim3((BB * TT) / 16), dim3(256), 0, stream, x, wbt, qo, ko, kt);
    hipLaunchKernelGGL(flash_kernel, dim3(BB * 64),        dim3(512), 0, stream, qo, ko, kt, out);
}